// Round 1
// baseline (590.753 us; speedup 1.0000x reference)
//
#include <hip/hip_runtime.h>

// Problem constants (fixed by the reference).
#define N_SPK 1024
#define M_UTT 32
#define D_EMB 512
#define NROWS (N_SPK * M_UTT)   // 32768

#define NEG_INF (-__builtin_inff())

// ---------------------------------------------------------------------------
// Kernel 1: centroids[n][d] = mean_m e[n][m][d].  524288 outputs.
// Consecutive threads -> consecutive d -> coalesced loads per m-slice.
// ---------------------------------------------------------------------------
__global__ void centroid_kernel(const float* __restrict__ e,
                                float* __restrict__ cent) {
    int gid = blockIdx.x * 256 + threadIdx.x;     // 0..524287
    int n = gid >> 9;                             // /512
    int d = gid & 511;
    const float* p = e + ((size_t)n * M_UTT) * D_EMB + d;
    float s = 0.f;
#pragma unroll
    for (int m = 0; m < M_UTT; ++m) s += p[(size_t)m * D_EMB];
    cent[gid] = s * (1.0f / M_UTT);
}

// ---------------------------------------------------------------------------
// Kernel 2: nsq[row] = sum_d e[row][d]^2, row = n*M+m.  One wave per row.
// ---------------------------------------------------------------------------
__global__ void normsq_kernel(const float* __restrict__ e,
                              float* __restrict__ nsq) {
    int wv = threadIdx.x >> 6;
    int lane = threadIdx.x & 63;
    int row = blockIdx.x * 4 + wv;
    const float* p = e + (size_t)row * D_EMB + lane;
    float s = 0.f;
#pragma unroll
    for (int j = 0; j < 8; ++j) { float x = p[j * 64]; s += x * x; }
#pragma unroll
    for (int off = 32; off; off >>= 1) s += __shfl_xor(s, off);
    if (lane == 0) nsq[row] = s;
}

// ---------------------------------------------------------------------------
// Main fused kernel: per block of 64 rows, GEMM against all 1024 centroids in
// 8 column tiles of 128, with online logsumexp per row.  256 threads,
// thread micro-tile 4 rows x 8 cols.
//   diag logit = w*(32*(e.c_own) + nsq/31) + b  (overwrites GEMM value)
//   row loss  = (m + log s) - diag_logit
// Block writes sum of its 64 row losses to partials[blk].
// ---------------------------------------------------------------------------
#define BR 64
#define BC 128
#define BK 16
#define TR 4
#define TC 8

__global__ __launch_bounds__(256, 2)
void ge2e_main(const float* __restrict__ e, const float* __restrict__ cent,
               const float* __restrict__ nsq, const float* __restrict__ wp,
               const float* __restrict__ bp, float* __restrict__ partials) {
    __shared__ float As[BK][BR];     // 4 KiB   As[k][row]
    __shared__ float Bs[BK][BC];     // 8 KiB   Bs[k][col]
    __shared__ float diagL[BR];
    __shared__ float red[16];

    const int tid = threadIdx.x;
    const int tx = tid & 15;         // col group: cols tx*8 .. tx*8+7
    const int ty = tid >> 4;         // row group: rows ty*4 .. ty*4+3
    const int blk = blockIdx.x;
    const int r0 = blk * BR;

    const float w = *wp;
    const float bb = *bp;

    float m_run[TR], s_run[TR];
#pragma unroll
    for (int i = 0; i < TR; ++i) { m_run[i] = NEG_INF; s_run[i] = 0.f; }

    // Staging assignments.
    // A: 64 rows x 16 k = 1024 floats; thread -> (row = tid/4, k = (tid%4)*4), one float4.
    const int a_row = tid >> 2;
    const int a_k   = (tid & 3) * 4;
    // B: 128 cols x 16 k = 2048 floats; thread -> (col = tid/2, k = (tid%2)*8), two float4.
    const int b_col = tid >> 1;
    const int b_k   = (tid & 1) * 8;

    for (int ct = 0; ct < N_SPK / BC; ++ct) {
        const int c0 = ct * BC;
        float acc[TR][TC];
#pragma unroll
        for (int i = 0; i < TR; ++i)
#pragma unroll
            for (int j = 0; j < TC; ++j) acc[i][j] = 0.f;

        for (int kk = 0; kk < D_EMB; kk += BK) {
            __syncthreads();
            // Stage A tile.
            {
                float4 av = *(const float4*)(e + (size_t)(r0 + a_row) * D_EMB + kk + a_k);
                As[a_k + 0][a_row] = av.x;
                As[a_k + 1][a_row] = av.y;
                As[a_k + 2][a_row] = av.z;
                As[a_k + 3][a_row] = av.w;
            }
            // Stage B tile.
            {
                const float* bp0 = cent + (size_t)(c0 + b_col) * D_EMB + kk + b_k;
                float4 bv0 = *(const float4*)(bp0);
                float4 bv1 = *(const float4*)(bp0 + 4);
                Bs[b_k + 0][b_col] = bv0.x;
                Bs[b_k + 1][b_col] = bv0.y;
                Bs[b_k + 2][b_col] = bv0.z;
                Bs[b_k + 3][b_col] = bv0.w;
                Bs[b_k + 4][b_col] = bv1.x;
                Bs[b_k + 5][b_col] = bv1.y;
                Bs[b_k + 6][b_col] = bv1.z;
                Bs[b_k + 7][b_col] = bv1.w;
            }
            __syncthreads();

#pragma unroll
            for (int k = 0; k < BK; ++k) {
                float4 a4 = *(const float4*)&As[k][ty * TR];
                float4 b4a = *(const float4*)&Bs[k][tx * TC];
                float4 b4b = *(const float4*)&Bs[k][tx * TC + 4];
                float av[TR] = {a4.x, a4.y, a4.z, a4.w};
                float bv[TC] = {b4a.x, b4a.y, b4a.z, b4a.w,
                                b4b.x, b4b.y, b4b.z, b4b.w};
#pragma unroll
                for (int i = 0; i < TR; ++i)
#pragma unroll
                    for (int j = 0; j < TC; ++j)
                        acc[i][j] = __builtin_fmaf(av[i], bv[j], acc[i][j]);
            }
        }

        // Epilogue for this column tile: logits, diag fix, online logsumexp.
#pragma unroll
        for (int i = 0; i < TR; ++i) {
            const int grow = r0 + ty * TR + i;
            const int dcol = grow >> 5;   // speaker index = row / 32
            float lv[TC];
#pragma unroll
            for (int j = 0; j < TC; ++j) {
                const int gcol = c0 + tx * TC + j;
                float v = acc[i][j];
                float lg;
                if (gcol == dcol) {
                    // diag = e.sum + ||e||^2/31 = 32*(e.cent) + nsq/31
                    lg = __builtin_fmaf(w, __builtin_fmaf(32.0f, v,
                             (1.0f / 31.0f) * nsq[grow]), bb);
                    diagL[ty * TR + i] = lg;
                } else {
                    lg = __builtin_fmaf(w, v, bb);
                }
                lv[j] = lg;
            }
            float mx = lv[0];
#pragma unroll
            for (int j = 1; j < TC; ++j) mx = fmaxf(mx, lv[j]);
#pragma unroll
            for (int off = 8; off; off >>= 1) mx = fmaxf(mx, __shfl_xor(mx, off));
            float ss = 0.f;
#pragma unroll
            for (int j = 0; j < TC; ++j) ss += __expf(lv[j] - mx);
#pragma unroll
            for (int off = 8; off; off >>= 1) ss += __shfl_xor(ss, off);
            // Merge (mx, ss) into running (m, s).
            float nm = fmaxf(m_run[i], mx);
            s_run[i] = s_run[i] * __expf(m_run[i] - nm) + ss * __expf(mx - nm);
            m_run[i] = nm;
        }
    }

    __syncthreads();   // diagL fully written
    if (tx == 0) {
        float part = 0.f;
#pragma unroll
        for (int i = 0; i < TR; ++i) {
            const int lr = ty * TR + i;
            part += m_run[i] + __logf(s_run[i]) - diagL[lr];
        }
        red[ty] = part;
    }
    __syncthreads();
    if (tid == 0) {
        float t = 0.f;
#pragma unroll
        for (int i = 0; i < 16; ++i) t += red[i];
        partials[blk] = t;
    }
}

// ---------------------------------------------------------------------------
// Final reduce: 512 block partials -> mean loss.
// ---------------------------------------------------------------------------
__global__ void reduce_kernel(const float* __restrict__ partials,
                              float* __restrict__ out) {
    __shared__ float red[4];
    int tid = threadIdx.x;   // 256 threads
    float v = partials[tid] + partials[tid + 256];
#pragma unroll
    for (int off = 32; off; off >>= 1) v += __shfl_xor(v, off);
    if ((tid & 63) == 0) red[tid >> 6] = v;
    __syncthreads();
    if (tid == 0)
        out[0] = (red[0] + red[1] + red[2] + red[3]) * (1.0f / NROWS);
}

extern "C" void kernel_launch(void* const* d_in, const int* in_sizes, int n_in,
                              void* d_out, int out_size, void* d_ws, size_t ws_size,
                              hipStream_t stream) {
    const float* e  = (const float*)d_in[0];   // [1024,32,512] f32
    const float* wp = (const float*)d_in[1];   // scalar
    const float* bp = (const float*)d_in[2];   // scalar
    float* out = (float*)d_out;

    float* ws = (float*)d_ws;
    float* cent     = ws;                       // 1024*512 = 524288 floats
    float* nsq      = ws + 524288;              // 32768 floats
    float* partials = ws + 524288 + 32768;      // 512 floats

    centroid_kernel<<<N_SPK * D_EMB / 256, 256, 0, stream>>>(e, cent);
    normsq_kernel<<<NROWS / 4, 256, 0, stream>>>(e, nsq);
    ge2e_main<<<NROWS / BR, 256, 0, stream>>>(e, cent, nsq, wp, bp, partials);
    reduce_kernel<<<1, 256, 0, stream>>>(partials, out);
}

// Round 2
// 259.959 us; speedup vs baseline: 2.2725x; 2.2725x over previous
//
#include <hip/hip_runtime.h>

// Problem constants (fixed by the reference).
#define N_SPK 1024
#define M_UTT 32
#define D_EMB 512
#define NROWS (N_SPK * M_UTT)   // 32768

#define NEG_INF (-__builtin_inff())

using f16x8 = __attribute__((ext_vector_type(8))) _Float16;
using f32x4 = __attribute__((ext_vector_type(4))) float;

// ===========================================================================
// FAST PATH (split-f16 MFMA).  Needs ~74 MB workspace.
// ===========================================================================

// Async global->LDS, 16 B per lane.  LDS dest is wave-uniform base + lane*16.
__device__ __forceinline__ void gload16(const void* g, void* lds) {
    __builtin_amdgcn_global_load_lds(
        (const __attribute__((address_space(1))) void*)g,
        (__attribute__((address_space(3))) void*)lds, 16, 0, 0);
}

// ---------------------------------------------------------------------------
// e_prep: per row (n*M+m): split e (fp32) -> e_hi,e_lo (f16), and nsq = ||e||^2.
// One wave per row; lane l handles elems l*8..l*8+7.
// ---------------------------------------------------------------------------
__global__ void e_prep_kernel(const float* __restrict__ e,
                              _Float16* __restrict__ ehi,
                              _Float16* __restrict__ elo,
                              float* __restrict__ nsq) {
    const int wv = threadIdx.x >> 6, l = threadIdx.x & 63;
    const int row = blockIdx.x * 4 + wv;
    const float* p = e + (size_t)row * D_EMB + l * 8;
    float4 x0 = *(const float4*)p;
    float4 x1 = *(const float4*)(p + 4);
    float xs[8] = {x0.x, x0.y, x0.z, x0.w, x1.x, x1.y, x1.z, x1.w};
    f16x8 h, lo;
    float ssq = 0.f;
#pragma unroll
    for (int j = 0; j < 8; ++j) {
        float x = xs[j];
        _Float16 hh = (_Float16)x;
        h[j] = hh;
        lo[j] = (_Float16)(x - (float)hh);
        ssq = __builtin_fmaf(x, x, ssq);
    }
    *(f16x8*)(ehi + (size_t)row * D_EMB + l * 8) = h;
    *(f16x8*)(elo + (size_t)row * D_EMB + l * 8) = lo;
#pragma unroll
    for (int off = 32; off; off >>= 1) ssq += __shfl_xor(ssq, off);
    if (l == 0) nsq[row] = ssq;
}

// ---------------------------------------------------------------------------
// c_prep: centroid (fp32 mean over M) -> c_hi,c_lo (f16).  524288 outputs.
// ---------------------------------------------------------------------------
__global__ void c_prep_kernel(const float* __restrict__ e,
                              _Float16* __restrict__ chi,
                              _Float16* __restrict__ clo) {
    int gid = blockIdx.x * 256 + threadIdx.x;    // 0..524287
    int n = gid >> 9;
    int d = gid & 511;
    const float* p = e + ((size_t)n * M_UTT) * D_EMB + d;
    float s = 0.f;
#pragma unroll
    for (int m = 0; m < M_UTT; ++m) s += p[(size_t)m * D_EMB];
    float c = s * (1.0f / M_UTT);
    _Float16 hh = (_Float16)c;
    chi[gid] = hh;
    clo[gid] = (_Float16)(c - (float)hh);
}

// ---------------------------------------------------------------------------
// gemm_ls: 128x128 logit tile per block via 3-pass split-f16 MFMA GEMM
// (hi*hi + hi*lo + lo*hi), fp32 accumulate. Grid (ct=8, rt=256), 256 thr.
// Epilogue: logits, diag substitution, per-wave 64-col (max,sumexp) partials
// -> pm[row][ct*2+wx]; diag logit -> diagL[row].
//
// LDS k-slot XOR swizzle: LDS[row][slot] holds global k-group (slot ^ (row&7)),
// applied on the *global address* side so global_load_lds's fixed
// base+lane*16 dest still works; makes fragment ds_read_b128 <=2-way.
// ---------------------------------------------------------------------------
__global__ __launch_bounds__(256, 2)
void gemm_ls_kernel(const _Float16* __restrict__ ehi,
                    const _Float16* __restrict__ elo,
                    const _Float16* __restrict__ chi,
                    const _Float16* __restrict__ clo,
                    const float* __restrict__ nsq,
                    const float* __restrict__ wp,
                    const float* __restrict__ bp,
                    float2* __restrict__ pm,
                    float* __restrict__ diagL) {
    __shared__ _Float16 At[128 * 64];   // 16 KiB  At[row][64 k-halves]
    __shared__ _Float16 Bt[128 * 64];   // 16 KiB  Bt[cent][64 k-halves]

    const int tid = threadIdx.x;
    const int wv = tid >> 6, l = tid & 63;
    const int wy = wv >> 1, wx = wv & 1;      // wave covers rows wy*64+, cols wx*64+
    const int ln = l & 15, q = l >> 4;
    const int ct = blockIdx.x, rt = blockIdx.y;
    const int r0 = rt * 128, c0 = ct * 128;

    f32x4 acc[4][4];
    f32x4 zz = {0.f, 0.f, 0.f, 0.f};
#pragma unroll
    for (int i = 0; i < 4; ++i)
#pragma unroll
        for (int j = 0; j < 4; ++j) acc[i][j] = zz;

    const _Float16* APs[3] = {ehi, ehi, elo};
    const _Float16* BPs[3] = {chi, clo, chi};

    const int srow_b = wv * 8 + (l >> 3);   // staging row within 32-chunk
    const int sslot = l & 7;

    for (int p = 0; p < 3; ++p) {
        const _Float16* A = APs[p] + (size_t)r0 * D_EMB;
        const _Float16* B = BPs[p] + (size_t)c0 * D_EMB;
        for (int kt = 0; kt < 8; ++kt) {
            const int kk = kt * 64;
            __syncthreads();   // previous tile's ds_reads done before overwrite
#pragma unroll
            for (int i = 0; i < 4; ++i) {
                int row = i * 32 + srow_b;
                int cg = (sslot ^ (row & 7)) * 8;
                gload16(A + (size_t)row * D_EMB + kk + cg,
                        &At[(i * 32 + wv * 8) * 64]);
                gload16(B + (size_t)row * D_EMB + kk + cg,
                        &Bt[(i * 32 + wv * 8) * 64]);
            }
            __syncthreads();   // drains vmcnt (loads landed) + all threads

#pragma unroll
            for (int ks = 0; ks < 2; ++ks) {
                f16x8 af[4], bf[4];
                const int slot = ((ks * 4 + q) ^ (ln & 7)) * 8;
#pragma unroll
                for (int mt = 0; mt < 4; ++mt)
                    af[mt] = *(const f16x8*)&At[(wy * 64 + mt * 16 + ln) * 64 + slot];
#pragma unroll
                for (int nt = 0; nt < 4; ++nt)
                    bf[nt] = *(const f16x8*)&Bt[(wx * 64 + nt * 16 + ln) * 64 + slot];
#pragma unroll
                for (int mt = 0; mt < 4; ++mt)
#pragma unroll
                    for (int nt = 0; nt < 4; ++nt)
                        acc[mt][nt] = __builtin_amdgcn_mfma_f32_16x16x32_f16(
                            af[mt], bf[nt], acc[mt][nt], 0, 0, 0);
            }
        }
    }

    // ---- Epilogue ----
    const float w = wp[0], bb = bp[0];
    const bool isDiag = (ct == (rt >> 5));   // this col-block holds the diag cols

#pragma unroll
    for (int mt = 0; mt < 4; ++mt) {
#pragma unroll
        for (int r = 0; r < 4; ++r) {
            const int grow = r0 + wy * 64 + mt * 16 + q * 4 + r;
            const float nsqv = isDiag ? nsq[grow] : 0.f;
            const int nloc = (grow >> 5) - c0;   // diag col, tile-local
            float lv[4];
#pragma unroll
            for (int nt = 0; nt < 4; ++nt) {
                float v = acc[mt][nt][r];
                float lg = __builtin_fmaf(w, v, bb);
                if (isDiag && (wx * 64 + nt * 16 + ln) == nloc) {
                    lg = __builtin_fmaf(
                        w, __builtin_fmaf(32.0f, v, nsqv * (1.0f / 31.0f)), bb);
                    diagL[grow] = lg;
                }
                lv[nt] = lg;
            }
            float mx = fmaxf(fmaxf(lv[0], lv[1]), fmaxf(lv[2], lv[3]));
#pragma unroll
            for (int off = 8; off; off >>= 1) mx = fmaxf(mx, __shfl_xor(mx, off));
            float ss = 0.f;
#pragma unroll
            for (int nt = 0; nt < 4; ++nt) ss += __expf(lv[nt] - mx);
#pragma unroll
            for (int off = 8; off; off >>= 1) ss += __shfl_xor(ss, off);
            if (ln == 0) {
                float2 v2; v2.x = mx; v2.y = ss;
                pm[(size_t)grow * 16 + ct * 2 + wx] = v2;
            }
        }
    }
}

// ---------------------------------------------------------------------------
// rowloss: merge 16 (m,s) partials per row -> loss_row, block-reduce sum.
// ---------------------------------------------------------------------------
__global__ void rowloss_kernel(const float2* __restrict__ pm,
                               const float* __restrict__ diagL,
                               float* __restrict__ bpart) {
    __shared__ float red[4];
    const int tid = threadIdx.x;
    const int row = blockIdx.x * 256 + tid;
    float M = NEG_INF, S = 0.f;
#pragma unroll
    for (int i = 0; i < 16; ++i) {
        float2 t = pm[(size_t)row * 16 + i];
        float nm = fmaxf(M, t.x);
        S = S * __expf(M - nm) + t.y * __expf(t.x - nm);
        M = nm;
    }
    float loss = M + __logf(S) - diagL[row];
#pragma unroll
    for (int off = 32; off; off >>= 1) loss += __shfl_xor(loss, off);
    if ((tid & 63) == 0) red[tid >> 6] = loss;
    __syncthreads();
    if (tid == 0) bpart[blockIdx.x] = red[0] + red[1] + red[2] + red[3];
}

__global__ void final_reduce_kernel(const float* __restrict__ bpart,
                                    float* __restrict__ out) {
    __shared__ float red[2];
    const int tid = threadIdx.x;   // 128 threads
    float v = bpart[tid];
#pragma unroll
    for (int off = 32; off; off >>= 1) v += __shfl_xor(v, off);
    if ((tid & 63) == 0) red[tid >> 6] = v;
    __syncthreads();
    if (tid == 0) out[0] = (red[0] + red[1]) * (1.0f / NROWS);
}

// ===========================================================================
// FALLBACK PATH (round-1 fp32 vector kernel) — used if ws_size is too small.
// ===========================================================================

__global__ void centroid_kernel(const float* __restrict__ e,
                                float* __restrict__ cent) {
    int gid = blockIdx.x * 256 + threadIdx.x;
    int n = gid >> 9;
    int d = gid & 511;
    const float* p = e + ((size_t)n * M_UTT) * D_EMB + d;
    float s = 0.f;
#pragma unroll
    for (int m = 0; m < M_UTT; ++m) s += p[(size_t)m * D_EMB];
    cent[gid] = s * (1.0f / M_UTT);
}

__global__ void normsq_kernel(const float* __restrict__ e,
                              float* __restrict__ nsq) {
    int wv = threadIdx.x >> 6;
    int lane = threadIdx.x & 63;
    int row = blockIdx.x * 4 + wv;
    const float* p = e + (size_t)row * D_EMB + lane;
    float s = 0.f;
#pragma unroll
    for (int j = 0; j < 8; ++j) { float x = p[j * 64]; s += x * x; }
#pragma unroll
    for (int off = 32; off; off >>= 1) s += __shfl_xor(s, off);
    if (lane == 0) nsq[row] = s;
}

#define BR 64
#define BC 128
#define BK 16
#define TR 4
#define TC 8

__global__ __launch_bounds__(256, 2)
void ge2e_main(const float* __restrict__ e, const float* __restrict__ cent,
               const float* __restrict__ nsq, const float* __restrict__ wp,
               const float* __restrict__ bp, float* __restrict__ partials) {
    __shared__ float As[BK][BR];
    __shared__ float Bs[BK][BC];
    __shared__ float diagLs[BR];
    __shared__ float red[16];

    const int tid = threadIdx.x;
    const int tx = tid & 15;
    const int ty = tid >> 4;
    const int blk = blockIdx.x;
    const int r0 = blk * BR;

    const float w = *wp;
    const float bb = *bp;

    float m_run[TR], s_run[TR];
#pragma unroll
    for (int i = 0; i < TR; ++i) { m_run[i] = NEG_INF; s_run[i] = 0.f; }

    const int a_row = tid >> 2;
    const int a_k   = (tid & 3) * 4;
    const int b_col = tid >> 1;
    const int b_k   = (tid & 1) * 8;

    for (int ct = 0; ct < N_SPK / BC; ++ct) {
        const int c0 = ct * BC;
        float acc[TR][TC];
#pragma unroll
        for (int i = 0; i < TR; ++i)
#pragma unroll
            for (int j = 0; j < TC; ++j) acc[i][j] = 0.f;

        for (int kk = 0; kk < D_EMB; kk += BK) {
            __syncthreads();
            {
                float4 av = *(const float4*)(e + (size_t)(r0 + a_row) * D_EMB + kk + a_k);
                As[a_k + 0][a_row] = av.x;
                As[a_k + 1][a_row] = av.y;
                As[a_k + 2][a_row] = av.z;
                As[a_k + 3][a_row] = av.w;
            }
            {
                const float* bp0 = cent + (size_t)(c0 + b_col) * D_EMB + kk + b_k;
                float4 bv0 = *(const float4*)(bp0);
                float4 bv1 = *(const float4*)(bp0 + 4);
                Bs[b_k + 0][b_col] = bv0.x;
                Bs[b_k + 1][b_col] = bv0.y;
                Bs[b_k + 2][b_col] = bv0.z;
                Bs[b_k + 3][b_col] = bv0.w;
                Bs[b_k + 4][b_col] = bv1.x;
                Bs[b_k + 5][b_col] = bv1.y;
                Bs[b_k + 6][b_col] = bv1.z;
                Bs[b_k + 7][b_col] = bv1.w;
            }
            __syncthreads();

#pragma unroll
            for (int k = 0; k < BK; ++k) {
                float4 a4 = *(const float4*)&As[k][ty * TR];
                float4 b4a = *(const float4*)&Bs[k][tx * TC];
                float4 b4b = *(const float4*)&Bs[k][tx * TC + 4];
                float av[TR] = {a4.x, a4.y, a4.z, a4.w};
                float bv[TC] = {b4a.x, b4a.y, b4a.z, b4a.w,
                                b4b.x, b4b.y, b4b.z, b4b.w};
#pragma unroll
                for (int i = 0; i < TR; ++i)
#pragma unroll
                    for (int j = 0; j < TC; ++j)
                        acc[i][j] = __builtin_fmaf(av[i], bv[j], acc[i][j]);
            }
        }

#pragma unroll
        for (int i = 0; i < TR; ++i) {
            const int grow = r0 + ty * TR + i;
            const int dcol = grow >> 5;
            float lv[TC];
#pragma unroll
            for (int j = 0; j < TC; ++j) {
                const int gcol = c0 + tx * TC + j;
                float v = acc[i][j];
                float lg;
                if (gcol == dcol) {
                    lg = __builtin_fmaf(w, __builtin_fmaf(32.0f, v,
                             (1.0f / 31.0f) * nsq[grow]), bb);
                    diagLs[ty * TR + i] = lg;
                } else {
                    lg = __builtin_fmaf(w, v, bb);
                }
                lv[j] = lg;
            }
            float mx = lv[0];
#pragma unroll
            for (int j = 1; j < TC; ++j) mx = fmaxf(mx, lv[j]);
#pragma unroll
            for (int off = 8; off; off >>= 1) mx = fmaxf(mx, __shfl_xor(mx, off));
            float ss = 0.f;
#pragma unroll
            for (int j = 0; j < TC; ++j) ss += __expf(lv[j] - mx);
#pragma unroll
            for (int off = 8; off; off >>= 1) ss += __shfl_xor(ss, off);
            float nm = fmaxf(m_run[i], mx);
            s_run[i] = s_run[i] * __expf(m_run[i] - nm) + ss * __expf(mx - nm);
            m_run[i] = nm;
        }
    }

    __syncthreads();
    if (tx == 0) {
        float part = 0.f;
#pragma unroll
        for (int i = 0; i < TR; ++i) {
            const int lr = ty * TR + i;
            part += m_run[i] + __logf(s_run[i]) - diagLs[lr];
        }
        red[ty] = part;
    }
    __syncthreads();
    if (tid == 0) {
        float t = 0.f;
#pragma unroll
        for (int i = 0; i < 16; ++i) t += red[i];
        partials[blk] = t;
    }
}

__global__ void reduce_kernel(const float* __restrict__ partials,
                              float* __restrict__ out) {
    __shared__ float red[4];
    int tid = threadIdx.x;
    float v = partials[tid] + partials[tid + 256];
#pragma unroll
    for (int off = 32; off; off >>= 1) v += __shfl_xor(v, off);
    if ((tid & 63) == 0) red[tid >> 6] = v;
    __syncthreads();
    if (tid == 0)
        out[0] = (red[0] + red[1] + red[2] + red[3]) * (1.0f / NROWS);
}

// ===========================================================================

extern "C" void kernel_launch(void* const* d_in, const int* in_sizes, int n_in,
                              void* d_out, int out_size, void* d_ws, size_t ws_size,
                              hipStream_t stream) {
    const float* e  = (const float*)d_in[0];   // [1024,32,512] f32
    const float* wp = (const float*)d_in[1];   // scalar
    const float* bp = (const float*)d_in[2];   // scalar
    float* out = (float*)d_out;

    // Fast-path workspace layout (bytes, all 256-aligned):
    //   ehi 33554432 | elo 33554432 | chi 1048576 | clo 1048576 |
    //   nsq 131072 | pm 4194304 | diagL 131072 | bpart 4096
    const size_t NEED_FAST = 33554432ull * 2 + 1048576ull * 2 + 131072ull
                           + 4194304ull + 131072ull + 4096ull;   // 73,666,560

    if (ws_size >= NEED_FAST) {
        char* base = (char*)d_ws;
        _Float16* ehi  = (_Float16*)(base);
        _Float16* elo  = (_Float16*)(base + 33554432ull);
        _Float16* chi  = (_Float16*)(base + 67108864ull);
        _Float16* clo  = (_Float16*)(base + 68157440ull);
        float*    nsq  = (float*)   (base + 69206016ull);
        float2*   pm   = (float2*)  (base + 69337088ull);
        float*    dgl  = (float*)   (base + 73531392ull);
        float*    bpart= (float*)   (base + 73662464ull);

        e_prep_kernel<<<NROWS / 4, 256, 0, stream>>>(e, ehi, elo, nsq);
        c_prep_kernel<<<N_SPK * D_EMB / 256, 256, 0, stream>>>(e, chi, clo);
        dim3 ggrid(8, 256);
        gemm_ls_kernel<<<ggrid, 256, 0, stream>>>(ehi, elo, chi, clo, nsq,
                                                  wp, bp, pm, dgl);
        rowloss_kernel<<<NROWS / 256, 256, 0, stream>>>(pm, dgl, bpart);
        final_reduce_kernel<<<1, 128, 0, stream>>>(bpart, out);
    } else {
        float* ws = (float*)d_ws;
        float* cent     = ws;
        float* nsq      = ws + 524288;
        float* partials = ws + 524288 + 32768;

        centroid_kernel<<<N_SPK * D_EMB / 256, 256, 0, stream>>>(e, cent);
        normsq_kernel<<<NROWS / 4, 256, 0, stream>>>(e, nsq);
        ge2e_main<<<NROWS / BR, 256, 0, stream>>>(e, cent, nsq, wp, bp, partials);
        reduce_kernel<<<1, 256, 0, stream>>>(partials, out);
    }
}

// Round 3
// 217.922 us; speedup vs baseline: 2.7108x; 1.1929x over previous
//
#include <hip/hip_runtime.h>

// Problem constants (fixed by the reference).
#define N_SPK 1024
#define M_UTT 32
#define D_EMB 512
#define NROWS (N_SPK * M_UTT)   // 32768

#define NEG_INF (-__builtin_inff())

using f16x8 = __attribute__((ext_vector_type(8))) _Float16;
using f32x4 = __attribute__((ext_vector_type(4))) float;

// ===========================================================================
// FAST PATH (split-f16 MFMA, fused 3-combo GEMM).  Needs ~74 MB workspace.
// ===========================================================================

// Async global->LDS, 16 B per lane. Global addr is per-lane; LDS dest is
// wave-uniform base + lane*16.
__device__ __forceinline__ void gload16(const void* g, void* lds) {
    __builtin_amdgcn_global_load_lds(
        (const __attribute__((address_space(1))) void*)g,
        (__attribute__((address_space(3))) void*)lds, 16, 0, 0);
}

// ---------------------------------------------------------------------------
// prep: one block per speaker n (32 rows x 512 dims, 64 KB fp32).
//  - split each row to ehi/elo (f16), nsq[row] = ||e_row||^2
//  - centroid via per-wave partials in LDS -> chi/clo (f16 split of fp32 mean)
// Reads e exactly once (fuses round-2's e_prep + c_prep second read of e).
// ---------------------------------------------------------------------------
__global__ __launch_bounds__(256)
void prep_kernel(const float* __restrict__ e,
                 _Float16* __restrict__ ehi, _Float16* __restrict__ elo,
                 _Float16* __restrict__ chi, _Float16* __restrict__ clo,
                 float* __restrict__ nsq) {
    __shared__ float csum[4][D_EMB];   // 8 KiB
    const int n = blockIdx.x;
    const int wv = threadIdx.x >> 6, l = threadIdx.x & 63;

    float cacc[8];
#pragma unroll
    for (int j = 0; j < 8; ++j) cacc[j] = 0.f;

#pragma unroll
    for (int mi = 0; mi < 8; ++mi) {
        const int m = mi * 4 + wv;
        const size_t row = (size_t)n * M_UTT + m;
        const float* p = e + row * D_EMB + l * 8;
        float4 x0 = *(const float4*)p;
        float4 x1 = *(const float4*)(p + 4);
        float xs[8] = {x0.x, x0.y, x0.z, x0.w, x1.x, x1.y, x1.z, x1.w};
        f16x8 h, lo2;
        float ssq = 0.f;
#pragma unroll
        for (int j = 0; j < 8; ++j) {
            float x = xs[j];
            _Float16 hh = (_Float16)x;
            h[j] = hh;
            lo2[j] = (_Float16)(x - (float)hh);   // x-hh exact (Sterbenz)
            cacc[j] += x;
            ssq = __builtin_fmaf(x, x, ssq);
        }
        *(f16x8*)(ehi + row * D_EMB + l * 8) = h;
        *(f16x8*)(elo + row * D_EMB + l * 8) = lo2;
#pragma unroll
        for (int off = 32; off; off >>= 1) ssq += __shfl_xor(ssq, off);
        if (l == 0) nsq[row] = ssq;
    }

#pragma unroll
    for (int j = 0; j < 8; ++j) csum[wv][l * 8 + j] = cacc[j];
    __syncthreads();
    for (int d = threadIdx.x; d < D_EMB; d += 256) {
        float c = (csum[0][d] + csum[1][d] + csum[2][d] + csum[3][d])
                  * (1.0f / M_UTT);
        _Float16 hh = (_Float16)c;
        chi[(size_t)n * D_EMB + d] = hh;
        clo[(size_t)n * D_EMB + d] = (_Float16)(c - (float)hh);
    }
}

// ---------------------------------------------------------------------------
// gemm_ls: 128x128 logit tile per block; per 32-half k-tile stage all four
// operand buffers (Ahi,Alo,Bhi,Blo; 8 KB each, wave w stages buffer w) and
// run the 3 MFMA combos hi*hi + hi*lo + lo*hi (fp32 acc).  16 k-tiles.
//
// LDS layout per buffer: 64 rows x 8 slots x 16 B.  Physical slot
// p = s ^ (r&7); logical s<4 -> (global row r, k-chunk s), s>=4 ->
// (global row r+64, k-chunk s-4).  Fragment ds_read_b128 is 2-way (free);
// staging is gload16 with per-lane swizzled global source, two 64 B lines
// per 8-lane group.
//
// XCD swizzle: blk -> xcd = blk&7 (round-robin dispatch), each XCD owns
// rt in [xcd*32, xcd*32+32), walking ct fastest -> concurrent A working
// set per XCD ~2 MB (fits 4 MB L2); A fetched ~once per XCD.
// ---------------------------------------------------------------------------
__global__ __launch_bounds__(256, 2)
void gemm_ls_kernel(const _Float16* __restrict__ ehi,
                    const _Float16* __restrict__ elo,
                    const _Float16* __restrict__ chi,
                    const _Float16* __restrict__ clo,
                    const float* __restrict__ nsq,
                    const float* __restrict__ wp,
                    const float* __restrict__ bp,
                    float2* __restrict__ pm,
                    float* __restrict__ diagL) {
    __shared__ _Float16 lds[4][64 * 64];   // 4 x 8 KiB = 32 KiB

    const int tid = threadIdx.x;
    const int wv = tid >> 6, l = tid & 63;
    const int wy = wv >> 1, wx = wv & 1;   // wave quadrant: rows wy*64+, cols wx*64+
    const int ln = l & 15, q = l >> 4;

    // XCD-aware decode of the 1-D grid (2048 blocks).
    const int blk = blockIdx.x;
    const int ct = (blk >> 3) & 7;
    const int rt = (blk & 7) * 32 + (blk >> 6);
    const int r0 = rt * 128, c0 = ct * 128;

    f32x4 acc[4][4];
    f32x4 zz = {0.f, 0.f, 0.f, 0.f};
#pragma unroll
    for (int i = 0; i < 4; ++i)
#pragma unroll
        for (int j = 0; j < 4; ++j) acc[i][j] = zz;

    // Wave w stages buffer w: 0=Ahi 1=Alo 2=Bhi 3=Blo.
    const _Float16* SB =
        (wv == 0) ? ehi + (size_t)r0 * D_EMB :
        (wv == 1) ? elo + (size_t)r0 * D_EMB :
        (wv == 2) ? chi + (size_t)c0 * D_EMB :
                    clo + (size_t)c0 * D_EMB;
    _Float16* dstbuf = lds[wv];
    const int s_l = (l & 7) ^ (l >> 3);                 // logical slot this lane feeds
    const int rowadd = (l >> 3) + ((s_l & 4) ? 64 : 0); // content-row offset
    const int kgofs = (s_l & 3) * 8;                    // k-chunk offset (halves)

    // Per-lane fragment LDS offsets (halves), fixed across k-tiles.
    int offA[4], offB[4];
#pragma unroll
    for (int t = 0; t < 4; ++t) {
        int mA = wy * 64 + t * 16 + ln;
        int pA = (((mA >> 6) << 2) + q) ^ (mA & 7);
        offA[t] = (mA & 63) * 64 + pA * 8;
        int mB = wx * 64 + t * 16 + ln;
        int pB = (((mB >> 6) << 2) + q) ^ (mB & 7);
        offB[t] = (mB & 63) * 64 + pB * 8;
    }

    for (int kt = 0; kt < 16; ++kt) {
        __syncthreads();   // previous tile's ds_reads done before overwrite
        const _Float16* src = SB + kt * 32 + kgofs;
#pragma unroll
        for (int c = 0; c < 8; ++c)
            gload16(src + (size_t)(c * 8 + rowadd) * D_EMB, dstbuf + c * 512);
        __syncthreads();   // vmcnt(0) drained by barrier semantics

        f16x8 af[4], bf[4], cf[4];
#pragma unroll
        for (int t = 0; t < 4; ++t) af[t] = *(const f16x8*)&lds[0][offA[t]];
#pragma unroll
        for (int t = 0; t < 4; ++t) bf[t] = *(const f16x8*)&lds[2][offB[t]];
#pragma unroll
        for (int i = 0; i < 4; ++i)
#pragma unroll
            for (int j = 0; j < 4; ++j)
                acc[i][j] = __builtin_amdgcn_mfma_f32_16x16x32_f16(
                    af[i], bf[j], acc[i][j], 0, 0, 0);
#pragma unroll
        for (int t = 0; t < 4; ++t) cf[t] = *(const f16x8*)&lds[1][offA[t]];  // Alo
#pragma unroll
        for (int i = 0; i < 4; ++i)
#pragma unroll
            for (int j = 0; j < 4; ++j)
                acc[i][j] = __builtin_amdgcn_mfma_f32_16x16x32_f16(
                    cf[i], bf[j], acc[i][j], 0, 0, 0);
#pragma unroll
        for (int t = 0; t < 4; ++t) cf[t] = *(const f16x8*)&lds[3][offB[t]];  // Blo
#pragma unroll
        for (int i = 0; i < 4; ++i)
#pragma unroll
            for (int j = 0; j < 4; ++j)
                acc[i][j] = __builtin_amdgcn_mfma_f32_16x16x32_f16(
                    af[i], cf[j], acc[i][j], 0, 0, 0);
    }

    // ---- Epilogue: logits, diag substitution, per-64-col (max,sumexp) ----
    const float w = wp[0], bb = bp[0];
    const bool isDiag = (ct == (rt >> 5));

#pragma unroll
    for (int mt = 0; mt < 4; ++mt) {
#pragma unroll
        for (int r = 0; r < 4; ++r) {
            const int grow = r0 + wy * 64 + mt * 16 + q * 4 + r;
            const float nsqv = isDiag ? nsq[grow] : 0.f;
            const int nloc = (grow >> 5) - c0;   // diag col, tile-local
            float lv[4];
#pragma unroll
            for (int nt = 0; nt < 4; ++nt) {
                float v = acc[mt][nt][r];
                float lg = __builtin_fmaf(w, v, bb);
                if (isDiag && (wx * 64 + nt * 16 + ln) == nloc) {
                    lg = __builtin_fmaf(
                        w, __builtin_fmaf(32.0f, v, nsqv * (1.0f / 31.0f)), bb);
                    diagL[grow] = lg;
                }
                lv[nt] = lg;
            }
            float mx = fmaxf(fmaxf(lv[0], lv[1]), fmaxf(lv[2], lv[3]));
#pragma unroll
            for (int off = 8; off; off >>= 1) mx = fmaxf(mx, __shfl_xor(mx, off));
            float ss = 0.f;
#pragma unroll
            for (int nt = 0; nt < 4; ++nt) ss += __expf(lv[nt] - mx);
#pragma unroll
            for (int off = 8; off; off >>= 1) ss += __shfl_xor(ss, off);
            if (ln == 0) {
                float2 v2; v2.x = mx; v2.y = ss;
                pm[(size_t)grow * 16 + ct * 2 + wx] = v2;
            }
        }
    }
}

// ---------------------------------------------------------------------------
// rowloss: merge 16 (m,s) partials per row -> loss_row, block-reduce sum.
// ---------------------------------------------------------------------------
__global__ void rowloss_kernel(const float2* __restrict__ pm,
                               const float* __restrict__ diagL,
                               float* __restrict__ bpart) {
    __shared__ float red[4];
    const int tid = threadIdx.x;
    const int row = blockIdx.x * 256 + tid;
    float M = NEG_INF, S = 0.f;
#pragma unroll
    for (int i = 0; i < 16; ++i) {
        float2 t = pm[(size_t)row * 16 + i];
        float nm = fmaxf(M, t.x);
        S = S * __expf(M - nm) + t.y * __expf(t.x - nm);
        M = nm;
    }
    float loss = M + __logf(S) - diagL[row];
#pragma unroll
    for (int off = 32; off; off >>= 1) loss += __shfl_xor(loss, off);
    if ((tid & 63) == 0) red[tid >> 6] = loss;
    __syncthreads();
    if (tid == 0) bpart[blockIdx.x] = red[0] + red[1] + red[2] + red[3];
}

__global__ void final_reduce_kernel(const float* __restrict__ bpart,
                                    float* __restrict__ out) {
    __shared__ float red[2];
    const int tid = threadIdx.x;   // 128 threads
    float v = bpart[tid];
#pragma unroll
    for (int off = 32; off; off >>= 1) v += __shfl_xor(v, off);
    if ((tid & 63) == 0) red[tid >> 6] = v;
    __syncthreads();
    if (tid == 0) out[0] = (red[0] + red[1]) * (1.0f / NROWS);
}

// ===========================================================================
// FALLBACK PATH (round-1 fp32 vector kernel) — used if ws_size is too small.
// ===========================================================================

__global__ void centroid_kernel(const float* __restrict__ e,
                                float* __restrict__ cent) {
    int gid = blockIdx.x * 256 + threadIdx.x;
    int n = gid >> 9;
    int d = gid & 511;
    const float* p = e + ((size_t)n * M_UTT) * D_EMB + d;
    float s = 0.f;
#pragma unroll
    for (int m = 0; m < M_UTT; ++m) s += p[(size_t)m * D_EMB];
    cent[gid] = s * (1.0f / M_UTT);
}

__global__ void normsq_kernel(const float* __restrict__ e,
                              float* __restrict__ nsq) {
    int wv = threadIdx.x >> 6;
    int lane = threadIdx.x & 63;
    int row = blockIdx.x * 4 + wv;
    const float* p = e + (size_t)row * D_EMB + lane;
    float s = 0.f;
#pragma unroll
    for (int j = 0; j < 8; ++j) { float x = p[j * 64]; s += x * x; }
#pragma unroll
    for (int off = 32; off; off >>= 1) s += __shfl_xor(s, off);
    if (lane == 0) nsq[row] = s;
}

#define BR 64
#define BC 128
#define BK 16
#define TR 4
#define TC 8

__global__ __launch_bounds__(256, 2)
void ge2e_main(const float* __restrict__ e, const float* __restrict__ cent,
               const float* __restrict__ nsq, const float* __restrict__ wp,
               const float* __restrict__ bp, float* __restrict__ partials) {
    __shared__ float As[BK][BR];
    __shared__ float Bs[BK][BC];
    __shared__ float diagLs[BR];
    __shared__ float red[16];

    const int tid = threadIdx.x;
    const int tx = tid & 15;
    const int ty = tid >> 4;
    const int blk = blockIdx.x;
    const int r0 = blk * BR;

    const float w = *wp;
    const float bb = *bp;

    float m_run[TR], s_run[TR];
#pragma unroll
    for (int i = 0; i < TR; ++i) { m_run[i] = NEG_INF; s_run[i] = 0.f; }

    const int a_row = tid >> 2;
    const int a_k   = (tid & 3) * 4;
    const int b_col = tid >> 1;
    const int b_k   = (tid & 1) * 8;

    for (int ct = 0; ct < N_SPK / BC; ++ct) {
        const int c0 = ct * BC;
        float acc[TR][TC];
#pragma unroll
        for (int i = 0; i < TR; ++i)
#pragma unroll
            for (int j = 0; j < TC; ++j) acc[i][j] = 0.f;

        for (int kk = 0; kk < D_EMB; kk += BK) {
            __syncthreads();
            {
                float4 av = *(const float4*)(e + (size_t)(r0 + a_row) * D_EMB + kk + a_k);
                As[a_k + 0][a_row] = av.x;
                As[a_k + 1][a_row] = av.y;
                As[a_k + 2][a_row] = av.z;
                As[a_k + 3][a_row] = av.w;
            }
            {
                const float* bp0 = cent + (size_t)(c0 + b_col) * D_EMB + kk + b_k;
                float4 bv0 = *(const float4*)(bp0);
                float4 bv1 = *(const float4*)(bp0 + 4);
                Bs[b_k + 0][b_col] = bv0.x;
                Bs[b_k + 1][b_col] = bv0.y;
                Bs[b_k + 2][b_col] = bv0.z;
                Bs[b_k + 3][b_col] = bv0.w;
                Bs[b_k + 4][b_col] = bv1.x;
                Bs[b_k + 5][b_col] = bv1.y;
                Bs[b_k + 6][b_col] = bv1.z;
                Bs[b_k + 7][b_col] = bv1.w;
            }
            __syncthreads();

#pragma unroll
            for (int k = 0; k < BK; ++k) {
                float4 a4 = *(const float4*)&As[k][ty * TR];
                float4 b4a = *(const float4*)&Bs[k][tx * TC];
                float4 b4b = *(const float4*)&Bs[k][tx * TC + 4];
                float av[TR] = {a4.x, a4.y, a4.z, a4.w};
                float bv[TC] = {b4a.x, b4a.y, b4a.z, b4a.w,
                                b4b.x, b4b.y, b4b.z, b4b.w};
#pragma unroll
                for (int i = 0; i < TR; ++i)
#pragma unroll
                    for (int j = 0; j < TC; ++j)
                        acc[i][j] = __builtin_fmaf(av[i], bv[j], acc[i][j]);
            }
        }

#pragma unroll
        for (int i = 0; i < TR; ++i) {
            const int grow = r0 + ty * TR + i;
            const int dcol = grow >> 5;
            float lv[TC];
#pragma unroll
            for (int j = 0; j < TC; ++j) {
                const int gcol = c0 + tx * TC + j;
                float v = acc[i][j];
                float lg;
                if (gcol == dcol) {
                    lg = __builtin_fmaf(w, __builtin_fmaf(32.0f, v,
                             (1.0f / 31.0f) * nsq[grow]), bb);
                    diagLs[ty * TR + i] = lg;
                } else {
                    lg = __builtin_fmaf(w, v, bb);
                }
                lv[j] = lg;
            }
            float mx = lv[0];
#pragma unroll
            for (int j = 1; j < TC; ++j) mx = fmaxf(mx, lv[j]);
#pragma unroll
            for (int off = 8; off; off >>= 1) mx = fmaxf(mx, __shfl_xor(mx, off));
            float ss = 0.f;
#pragma unroll
            for (int j = 0; j < TC; ++j) ss += __expf(lv[j] - mx);
#pragma unroll
            for (int off = 8; off; off >>= 1) ss += __shfl_xor(ss, off);
            float nm = fmaxf(m_run[i], mx);
            s_run[i] = s_run[i] * __expf(m_run[i] - nm) + ss * __expf(mx - nm);
            m_run[i] = nm;
        }
    }

    __syncthreads();
    if (tx == 0) {
        float part = 0.f;
#pragma unroll
        for (int i = 0; i < TR; ++i) {
            const int lr = ty * TR + i;
            part += m_run[i] + __logf(s_run[i]) - diagLs[lr];
        }
        red[ty] = part;
    }
    __syncthreads();
    if (tid == 0) {
        float t = 0.f;
#pragma unroll
        for (int i = 0; i < 16; ++i) t += red[i];
        partials[blk] = t;
    }
}

__global__ void reduce_kernel(const float* __restrict__ partials,
                              float* __restrict__ out) {
    __shared__ float red[4];
    int tid = threadIdx.x;
    float v = partials[tid] + partials[tid + 256];
#pragma unroll
    for (int off = 32; off; off >>= 1) v += __shfl_xor(v, off);
    if ((tid & 63) == 0) red[tid >> 6] = v;
    __syncthreads();
    if (tid == 0)
        out[0] = (red[0] + red[1] + red[2] + red[3]) * (1.0f / NROWS);
}

// ===========================================================================

extern "C" void kernel_launch(void* const* d_in, const int* in_sizes, int n_in,
                              void* d_out, int out_size, void* d_ws, size_t ws_size,
                              hipStream_t stream) {
    const float* e  = (const float*)d_in[0];   // [1024,32,512] f32
    const float* wp = (const float*)d_in[1];   // scalar
    const float* bp = (const float*)d_in[2];   // scalar
    float* out = (float*)d_out;

    // Fast-path workspace layout (bytes, all 256-aligned):
    //   ehi 33554432 | elo 33554432 | chi 1048576 | clo 1048576 |
    //   nsq 131072 | pm 4194304 | diagL 131072 | bpart 4096
    const size_t NEED_FAST = 33554432ull * 2 + 1048576ull * 2 + 131072ull
                           + 4194304ull + 131072ull + 4096ull;   // 73,666,560

    if (ws_size >= NEED_FAST) {
        char* base = (char*)d_ws;
        _Float16* ehi  = (_Float16*)(base);
        _Float16* elo  = (_Float16*)(base + 33554432ull);
        _Float16* chi  = (_Float16*)(base + 67108864ull);
        _Float16* clo  = (_Float16*)(base + 68157440ull);
        float*    nsq  = (float*)   (base + 69206016ull);
        float2*   pm   = (float2*)  (base + 69337088ull);
        float*    dgl  = (float*)   (base + 73531392ull);
        float*    bpart= (float*)   (base + 73662464ull);

        prep_kernel<<<N_SPK, 256, 0, stream>>>(e, ehi, elo, chi, clo, nsq);
        gemm_ls_kernel<<<2048, 256, 0, stream>>>(ehi, elo, chi, clo, nsq,
                                                 wp, bp, pm, dgl);
        rowloss_kernel<<<NROWS / 256, 256, 0, stream>>>(pm, dgl, bpart);
        final_reduce_kernel<<<1, 128, 0, stream>>>(bpart, out);
    } else {
        float* ws = (float*)d_ws;
        float* cent     = ws;
        float* nsq      = ws + 524288;
        float* partials = ws + 524288 + 32768;

        centroid_kernel<<<N_SPK * D_EMB / 256, 256, 0, stream>>>(e, cent);
        normsq_kernel<<<NROWS / 4, 256, 0, stream>>>(e, nsq);
        ge2e_main<<<NROWS / BR, 256, 0, stream>>>(e, cent, nsq, wp, bp, partials);
        reduce_kernel<<<1, 256, 0, stream>>>(partials, out);
    }
}